// Round 1
// baseline (235.264 us; speedup 1.0000x reference)
//
#include <hip/hip_runtime.h>

// HenonLayer: 4x { t=tanh(Y@W_in+b); grad=((1-t^2)*W_out)@W_in.T; X'=Y+eta; Y'=-X+grad }
// B=2e6, DIM=2, NI=64, fp32. eps=1.
//
// Round-4: (a) 4-way shared reciprocal -- one v_rcp_f32 per 2 row-pairs per neuron
// (was 2 per pair), recovered with full-rate muls; q clamped to [1, 5e4] so the
// 4-product stays in normal fp32 range (clamp only engages where sech^2 < 2e-5).
// (b) per-neuron constants packed into one contiguous 64B record so the scalar
// loads merge (s_load_dwordx8 + x2 instead of 5 scattered s_load_dwordx2).
// sech^2(a) = rcp(cosh^2(a)), cosh^2 = deg-5 all-positive Taylor in x=a^2
// (monotone >= 1, saturates cleanly, no branches; abs err <= ~3e-4).

#define NI 64

#define D5 1.410934744e-4f
#define D4 3.174603175e-3f
#define D3 4.444444444e-2f
#define D2 3.333333333e-1f
#define QCLAMP 5.0e4f

typedef float v2f __attribute__((ext_vector_type(2)));

__device__ __forceinline__ v2f splat(float s) { return (v2f){s, s}; }
__device__ __forceinline__ v2f vfma(v2f a, v2f b, v2f c) {
  return __builtin_elementwise_fma(a, b, c);
}

// d_ws table (floats):
//   [16*i .. 16*i+9]  neuron-i record: w0,w0, w1,w1, b,b, c0,c0, c1,c1 (pads to 16)
//   [1024],[1025]     eta0, eta1
__global__ __launch_bounds__(64) void henon_prep(
    const float* __restrict__ W_in, const float* __restrict__ W_out,
    const float* __restrict__ b_in, const float* __restrict__ eta,
    float* __restrict__ P) {
  int i = threadIdx.x;
  float w0 = W_in[i];
  float w1 = W_in[NI + i];
  float b = b_in[i];
  float wo = W_out[i];
  float c0 = wo * w0, c1 = wo * w1;
  float* R = P + (i << 4);
  R[0] = w0; R[1] = w0;
  R[2] = w1; R[3] = w1;
  R[4] = b;  R[5] = b;
  R[6] = c0; R[7] = c0;
  R[8] = c1; R[9] = c1;
  R[10] = 0.f; R[11] = 0.f; R[12] = 0.f; R[13] = 0.f; R[14] = 0.f; R[15] = 0.f;
  if (i < 2) P[1024 + i] = eta[i];
}

__global__ __launch_bounds__(256) void henon8(
    const float4* __restrict__ z, const float* __restrict__ P,
    float4* __restrict__ out, int batch) {
  float e0 = P[1024], e1 = P[1025];

  int tid = blockIdx.x * blockDim.x + threadIdx.x;
  int nthr = gridDim.x * blockDim.x;
  int ngroups = batch >> 3;

  for (int g = tid; g < ngroups; g += nthr) {
    int r = g << 3;
    float4 v[8];
#pragma unroll
    for (int k = 0; k < 8; ++k) v[k] = z[r + k];

    v2f X0[4], X1[4], Y0[4], Y1[4];
#pragma unroll
    for (int p = 0; p < 4; ++p) {
      X0[p] = (v2f){v[2 * p].x, v[2 * p + 1].x};
      X1[p] = (v2f){v[2 * p].y, v[2 * p + 1].y};
      Y0[p] = (v2f){v[2 * p].z, v[2 * p + 1].z};
      Y1[p] = (v2f){v[2 * p].w, v[2 * p + 1].w};
    }

    for (int it = 0; it < 4; ++it) {
      v2f g0[4], g1[4];
#pragma unroll
      for (int p = 0; p < 4; ++p) { g0[p] = splat(0.f); g1[p] = splat(0.f); }
#pragma unroll
      for (int i = 0; i < NI; ++i) {
        const v2f* __restrict__ Rp = (const v2f*)(P + (i << 4));
        v2f w0 = Rp[0], w1 = Rp[1], b = Rp[2], c0 = Rp[3], c1 = Rp[4];
        v2f q[4];
#pragma unroll
        for (int p = 0; p < 4; ++p) {
          v2f a = vfma(Y0[p], w0, vfma(Y1[p], w1, b));
          v2f x = a * a;
          v2f t = vfma(x, splat(D5), splat(D4));
          t = vfma(t, x, splat(D3));
          t = vfma(t, x, splat(D2));
          t = vfma(t, x, splat(1.0f));
          t = vfma(t, x, splat(1.0f));
          // clamp so the 4-way product below stays in normal fp32 range;
          // only engages where sech^2 < 2e-5 (negligible vs tolerance)
          q[p] = __builtin_elementwise_min(t, splat(QCLAMP));
        }
        // one reciprocal per 2 pairs: r = 1/(q0*q1*q2*q3), recover each 1/qk
        // with full-rate muls (trans-pipe traffic cut 4x vs per-component rcp)
#pragma unroll
        for (int h = 0; h < 2; ++h) {
          v2f qA = q[2 * h], qB = q[2 * h + 1];
          v2f P2 = qA * qB;               // {q0*q2, q1*q3}
          float prod = P2.x * P2.y;       // q0*q1*q2*q3  in [1, 6.25e18]
          float rr = __builtin_amdgcn_rcpf(prod);
          float rx = rr * P2.x;           // 1/(q1*q3)
          float ry = rr * P2.y;           // 1/(q0*q2)
          v2f sA = (v2f){ry * qB.x, rx * qB.y};   // {1/q0, 1/q1}
          v2f sB = (v2f){ry * qA.x, rx * qA.y};   // {1/q2, 1/q3}
          g0[2 * h]     = vfma(sA, c0, g0[2 * h]);
          g1[2 * h]     = vfma(sA, c1, g1[2 * h]);
          g0[2 * h + 1] = vfma(sB, c0, g0[2 * h + 1]);
          g1[2 * h + 1] = vfma(sB, c1, g1[2 * h + 1]);
        }
      }
#pragma unroll
      for (int p = 0; p < 4; ++p) {
        v2f nX0 = Y0[p] + splat(e0);
        v2f nX1 = Y1[p] + splat(e1);
        Y0[p] = g0[p] - X0[p];
        Y1[p] = g1[p] - X1[p];
        X0[p] = nX0;
        X1[p] = nX1;
      }
    }
#pragma unroll
    for (int p = 0; p < 4; ++p) {
      out[r + 2 * p]     = make_float4(X0[p].x, X1[p].x, Y0[p].x, Y1[p].x);
      out[r + 2 * p + 1] = make_float4(X0[p].y, X1[p].y, Y0[p].y, Y1[p].y);
    }
  }

  // Tail rows (batch % 8), scalar path.
  int tail = batch & 7;
  if (tail && tid < tail) {
    int row = (ngroups << 3) + tid;
    float4 v = z[row];
    float X0 = v.x, X1 = v.y, Y0 = v.z, Y1 = v.w;
    for (int it = 0; it < 4; ++it) {
      float g0 = 0.f, g1 = 0.f;
      for (int i = 0; i < NI; ++i) {
        const float* R = P + (i << 4);
        float a = fmaf(Y0, R[0], fmaf(Y1, R[2], R[4]));
        float x = a * a;
        float q = fmaf(x, D5, D4);
        q = fmaf(q, x, D3);
        q = fmaf(q, x, D2);
        q = fmaf(q, x, 1.0f);
        q = fmaf(q, x, 1.0f);
        float s = __builtin_amdgcn_rcpf(q);
        g0 = fmaf(s, R[6], g0);
        g1 = fmaf(s, R[8], g1);
      }
      float nX0 = Y0 + e0, nX1 = Y1 + e1;
      Y0 = g0 - X0;
      Y1 = g1 - X1;
      X0 = nX0;
      X1 = nX1;
    }
    out[row] = make_float4(X0, X1, Y0, Y1);
  }
}

// Fallback if ws too small for the table: raw weights, 1 row/thread.
__global__ __launch_bounds__(256) void henon_raw(
    const float4* __restrict__ z, const float* __restrict__ W_in,
    const float* __restrict__ W_out, const float* __restrict__ b_in,
    const float* __restrict__ eta, float4* __restrict__ out, int batch) {
  int idx = blockIdx.x * blockDim.x + threadIdx.x;
  int stride = gridDim.x * blockDim.x;
  float e0 = eta[0], e1 = eta[1];
  for (int row = idx; row < batch; row += stride) {
    float4 v = z[row];
    float X0 = v.x, X1 = v.y, Y0 = v.z, Y1 = v.w;
    for (int it = 0; it < 4; ++it) {
      float g0 = 0.f, g1 = 0.f;
#pragma unroll
      for (int i = 0; i < NI; ++i) {
        float w0 = W_in[i], w1 = W_in[NI + i];
        float a = fmaf(Y0, w0, fmaf(Y1, w1, b_in[i]));
        float x = a * a;
        float q = fmaf(x, D5, D4);
        q = fmaf(q, x, D3);
        q = fmaf(q, x, D2);
        q = fmaf(q, x, 1.0f);
        q = fmaf(q, x, 1.0f);
        float s = __builtin_amdgcn_rcpf(q) * W_out[i];
        g0 = fmaf(s, w0, g0);
        g1 = fmaf(s, w1, g1);
      }
      float nX0 = Y0 + e0, nX1 = Y1 + e1;
      Y0 = g0 - X0;
      Y1 = g1 - X1;
      X0 = nX0;
      X1 = nX1;
    }
    out[row] = make_float4(X0, X1, Y0, Y1);
  }
}

extern "C" void kernel_launch(void* const* d_in, const int* in_sizes, int n_in,
                              void* d_out, int out_size, void* d_ws, size_t ws_size,
                              hipStream_t stream) {
  const float4* z = (const float4*)d_in[0];
  const float* W_in = (const float*)d_in[1];
  const float* W_out = (const float*)d_in[2];
  const float* b_in = (const float*)d_in[3];
  const float* eta = (const float*)d_in[4];
  float4* out = (float4*)d_out;

  int batch = in_sizes[0] / 4;  // 2,000,000 rows

  if (ws_size >= 1026 * sizeof(float)) {
    float* P = (float*)d_ws;
    henon_prep<<<1, 64, 0, stream>>>(W_in, W_out, b_in, eta, P);
    int ngroups = (batch + 7) >> 3;
    int blocks = (ngroups + 255) / 256;
    henon8<<<blocks, 256, 0, stream>>>(z, P, out, batch);
  } else {
    int blocks = (batch + 255) / 256;
    henon_raw<<<blocks, 256, 0, stream>>>(z, W_in, W_out, b_in, eta, out, batch);
  }
}

// Round 2
// 231.895 us; speedup vs baseline: 1.0145x; 1.0145x over previous
//
#include <hip/hip_runtime.h>

// HenonLayer: 4x { t=tanh(Y@W_in+b); grad=((1-t^2)*W_out)@W_in.T; X'=Y+eta; Y'=-X+grad }
// B=2e6, DIM=2, NI=64, fp32. eps=1.
//
// Round-5: revert round-4's shared-reciprocal (regressed 14%: extra scalar muls +
// serial recovery chain cost more than 6 saved trans ops). Back to round-3
// structure (v_pk_fma via ext_vector_type(2), duplicated-pair constant planes,
// per-component v_rcp). SINGLE CHANGE vs round-3: 4 rows/thread instead of 8.
// Round-3 at 8 rows/thread launched only 976 blocks = 3904 waves vs 8192-wave
// machine capacity (<=48% fill, OccupancyPercent ~28, VALUBusy stuck at 76%).
// 4 rows/thread -> 1954 blocks = 7816 waves ~ 95% fill; per-row instruction
// count unchanged, wave-level parallelism 2x to cover rcp/fma chain latency.
// sech^2(a) = rcp(cosh^2(a)), cosh^2 = deg-5 all-positive Taylor in x=a^2
// (monotone >= 1, saturates cleanly, no branches; abs err <= ~3e-4).

#define NI 64

#define D5 1.410934744e-4f
#define D4 3.174603175e-3f
#define D3 4.444444444e-2f
#define D2 3.333333333e-1f

typedef float v2f __attribute__((ext_vector_type(2)));

__device__ __forceinline__ v2f splat(float s) { return (v2f){s, s}; }
__device__ __forceinline__ v2f vfma(v2f a, v2f b, v2f c) {
  return __builtin_elementwise_fma(a, b, c);
}
__device__ __forceinline__ v2f vrcp(v2f a) {
  v2f r;
  r.x = __builtin_amdgcn_rcpf(a.x);
  r.y = __builtin_amdgcn_rcpf(a.y);
  return r;
}

// d_ws table (floats): [0:128) w0 pairs | [128:256) w1 pairs | [256:384) b pairs
// | [384:512) c0 pairs | [512:640) c1 pairs | [640],[641] eta
__global__ __launch_bounds__(64) void henon_prep(
    const float* __restrict__ W_in, const float* __restrict__ W_out,
    const float* __restrict__ b_in, const float* __restrict__ eta,
    float* __restrict__ P) {
  int i = threadIdx.x;
  float w0 = W_in[i];
  float w1 = W_in[NI + i];
  float b = b_in[i];
  float wo = W_out[i];
  P[2 * i] = w0;       P[2 * i + 1] = w0;
  P[128 + 2 * i] = w1; P[128 + 2 * i + 1] = w1;
  P[256 + 2 * i] = b;  P[256 + 2 * i + 1] = b;
  float c0 = wo * w0, c1 = wo * w1;
  P[384 + 2 * i] = c0; P[384 + 2 * i + 1] = c0;
  P[512 + 2 * i] = c1; P[512 + 2 * i + 1] = c1;
  if (i < 2) P[640 + i] = eta[i];
}

__global__ __launch_bounds__(256) void henon4(
    const float4* __restrict__ z, const float* __restrict__ P,
    float4* __restrict__ out, int batch) {
  const v2f* __restrict__ Pw0 = (const v2f*)P;
  const v2f* __restrict__ Pw1 = (const v2f*)(P + 128);
  const v2f* __restrict__ Pb  = (const v2f*)(P + 256);
  const v2f* __restrict__ Pc0 = (const v2f*)(P + 384);
  const v2f* __restrict__ Pc1 = (const v2f*)(P + 512);
  float e0 = P[640], e1 = P[641];

  int tid = blockIdx.x * blockDim.x + threadIdx.x;
  int nthr = gridDim.x * blockDim.x;
  int ngroups = batch >> 2;

  for (int g = tid; g < ngroups; g += nthr) {
    int r = g << 2;
    float4 v[4];
#pragma unroll
    for (int k = 0; k < 4; ++k) v[k] = z[r + k];

    v2f X0[2], X1[2], Y0[2], Y1[2];
#pragma unroll
    for (int p = 0; p < 2; ++p) {
      X0[p] = (v2f){v[2 * p].x, v[2 * p + 1].x};
      X1[p] = (v2f){v[2 * p].y, v[2 * p + 1].y};
      Y0[p] = (v2f){v[2 * p].z, v[2 * p + 1].z};
      Y1[p] = (v2f){v[2 * p].w, v[2 * p + 1].w};
    }

    for (int it = 0; it < 4; ++it) {
      v2f g0[2], g1[2];
#pragma unroll
      for (int p = 0; p < 2; ++p) { g0[p] = splat(0.f); g1[p] = splat(0.f); }
#pragma unroll
      for (int i = 0; i < NI; ++i) {
        v2f w0 = Pw0[i], w1 = Pw1[i], b = Pb[i];
        v2f c0 = Pc0[i], c1 = Pc1[i];
#pragma unroll
        for (int p = 0; p < 2; ++p) {
          v2f a = vfma(Y0[p], w0, vfma(Y1[p], w1, b));
          v2f x = a * a;
          v2f q = vfma(x, splat(D5), splat(D4));
          q = vfma(q, x, splat(D3));
          q = vfma(q, x, splat(D2));
          q = vfma(q, x, splat(1.0f));
          q = vfma(q, x, splat(1.0f));
          v2f s = vrcp(q);
          g0[p] = vfma(s, c0, g0[p]);
          g1[p] = vfma(s, c1, g1[p]);
        }
      }
#pragma unroll
      for (int p = 0; p < 2; ++p) {
        v2f nX0 = Y0[p] + splat(e0);
        v2f nX1 = Y1[p] + splat(e1);
        Y0[p] = g0[p] - X0[p];
        Y1[p] = g1[p] - X1[p];
        X0[p] = nX0;
        X1[p] = nX1;
      }
    }
#pragma unroll
    for (int p = 0; p < 2; ++p) {
      out[r + 2 * p]     = make_float4(X0[p].x, X1[p].x, Y0[p].x, Y1[p].x);
      out[r + 2 * p + 1] = make_float4(X0[p].y, X1[p].y, Y0[p].y, Y1[p].y);
    }
  }

  // Tail rows (batch % 4), scalar path.
  int tail = batch & 3;
  if (tail && tid < tail) {
    int row = (ngroups << 2) + tid;
    float4 v = z[row];
    float X0 = v.x, X1 = v.y, Y0 = v.z, Y1 = v.w;
    for (int it = 0; it < 4; ++it) {
      float g0 = 0.f, g1 = 0.f;
      for (int i = 0; i < NI; ++i) {
        float a = fmaf(Y0, Pw0[i].x, fmaf(Y1, Pw1[i].x, Pb[i].x));
        float x = a * a;
        float q = fmaf(x, D5, D4);
        q = fmaf(q, x, D3);
        q = fmaf(q, x, D2);
        q = fmaf(q, x, 1.0f);
        q = fmaf(q, x, 1.0f);
        float s = __builtin_amdgcn_rcpf(q);
        g0 = fmaf(s, Pc0[i].x, g0);
        g1 = fmaf(s, Pc1[i].x, g1);
      }
      float nX0 = Y0 + e0, nX1 = Y1 + e1;
      Y0 = g0 - X0;
      Y1 = g1 - X1;
      X0 = nX0;
      X1 = nX1;
    }
    out[row] = make_float4(X0, X1, Y0, Y1);
  }
}

// Fallback if ws too small for the table: raw weights, 1 row/thread.
__global__ __launch_bounds__(256) void henon_raw(
    const float4* __restrict__ z, const float* __restrict__ W_in,
    const float* __restrict__ W_out, const float* __restrict__ b_in,
    const float* __restrict__ eta, float4* __restrict__ out, int batch) {
  int idx = blockIdx.x * blockDim.x + threadIdx.x;
  int stride = gridDim.x * blockDim.x;
  float e0 = eta[0], e1 = eta[1];
  for (int row = idx; row < batch; row += stride) {
    float4 v = z[row];
    float X0 = v.x, X1 = v.y, Y0 = v.z, Y1 = v.w;
    for (int it = 0; it < 4; ++it) {
      float g0 = 0.f, g1 = 0.f;
#pragma unroll
      for (int i = 0; i < NI; ++i) {
        float w0 = W_in[i], w1 = W_in[NI + i];
        float a = fmaf(Y0, w0, fmaf(Y1, w1, b_in[i]));
        float x = a * a;
        float q = fmaf(x, D5, D4);
        q = fmaf(q, x, D3);
        q = fmaf(q, x, D2);
        q = fmaf(q, x, 1.0f);
        q = fmaf(q, x, 1.0f);
        float s = __builtin_amdgcn_rcpf(q) * W_out[i];
        g0 = fmaf(s, w0, g0);
        g1 = fmaf(s, w1, g1);
      }
      float nX0 = Y0 + e0, nX1 = Y1 + e1;
      Y0 = g0 - X0;
      Y1 = g1 - X1;
      X0 = nX0;
      X1 = nX1;
    }
    out[row] = make_float4(X0, X1, Y0, Y1);
  }
}

extern "C" void kernel_launch(void* const* d_in, const int* in_sizes, int n_in,
                              void* d_out, int out_size, void* d_ws, size_t ws_size,
                              hipStream_t stream) {
  const float4* z = (const float4*)d_in[0];
  const float* W_in = (const float*)d_in[1];
  const float* W_out = (const float*)d_in[2];
  const float* b_in = (const float*)d_in[3];
  const float* eta = (const float*)d_in[4];
  float4* out = (float4*)d_out;

  int batch = in_sizes[0] / 4;  // 2,000,000 rows

  if (ws_size >= 642 * sizeof(float)) {
    float* P = (float*)d_ws;
    henon_prep<<<1, 64, 0, stream>>>(W_in, W_out, b_in, eta, P);
    int ngroups = (batch + 3) >> 2;
    int blocks = (ngroups + 255) / 256;
    henon4<<<blocks, 256, 0, stream>>>(z, P, out, batch);
  } else {
    int blocks = (batch + 255) / 256;
    henon_raw<<<blocks, 256, 0, stream>>>(z, W_in, W_out, b_in, eta, out, batch);
  }
}

// Round 3
// 191.812 us; speedup vs baseline: 1.2265x; 1.2090x over previous
//
#include <hip/hip_runtime.h>

// HenonLayer: 4x { t=tanh(Y@W_in+b); grad=((1-t^2)*W_out)@W_in.T; X'=Y+eta; Y'=-X+grad }
// B=2e6, DIM=2, NI=64, fp32. eps=1.
//
// Round-6: back to round-3's 8-rows/thread (measured best, 161us; round-5's
// 4-row variant regressed to 176us -- occupancy was not the binding constraint).
// SINGLE experimental change: force packed-f32 math via inline asm
// (v_pk_fma_f32 / v_pk_mul_f32). Busy-cycle arithmetic says round-3 issued
// ~3.0e8 SIMD-cycles vs ~1.4e8 for the ideal packed stream -- consistent with
// LLVM scalarizing the <2 x float> ops. Asm operands respect the <=1 SGPR
// read per VOP3P: per-neuron w0/w1/c0/c1 consumed straight from SGPR pairs
// (one per instruction), b + poly constants in VGPR pairs.
// sech^2(a) = rcp(cosh^2(a)), cosh^2 = deg-5 all-positive Taylor in x=a^2
// (monotone >= 1, saturates cleanly, no branches; abs err <= ~3e-4).

#define NI 64

#define D5 1.410934744e-4f
#define D4 3.174603175e-3f
#define D3 4.444444444e-2f
#define D2 3.333333333e-1f

typedef float v2f __attribute__((ext_vector_type(2)));

__device__ __forceinline__ v2f splat(float s) { return (v2f){s, s}; }

// d = a*b + c, b from SGPR pair (uniform), a/c VGPR pairs.
__device__ __forceinline__ v2f pk_fma_vsv(v2f a, v2f b, v2f c) {
  v2f d;
  asm("v_pk_fma_f32 %0, %1, %2, %3" : "=v"(d) : "v"(a), "s"(b), "v"(c));
  return d;
}
// d = a*b + c, c from SGPR pair (uniform constant), a/b VGPR pairs.
__device__ __forceinline__ v2f pk_fma_vvs(v2f a, v2f b, v2f c) {
  v2f d;
  asm("v_pk_fma_f32 %0, %1, %2, %3" : "=v"(d) : "v"(a), "v"(b), "s"(c));
  return d;
}
// d = a*b, all VGPR.
__device__ __forceinline__ v2f pk_mul_vv(v2f a, v2f b) {
  v2f d;
  asm("v_pk_mul_f32 %0, %1, %2" : "=v"(d) : "v"(a), "v"(b));
  return d;
}

// d_ws table (floats): [0:128) w0 pairs | [128:256) w1 pairs | [256:384) b pairs
// | [384:512) c0 pairs | [512:640) c1 pairs | [640],[641] eta
__global__ __launch_bounds__(64) void henon_prep(
    const float* __restrict__ W_in, const float* __restrict__ W_out,
    const float* __restrict__ b_in, const float* __restrict__ eta,
    float* __restrict__ P) {
  int i = threadIdx.x;
  float w0 = W_in[i];
  float w1 = W_in[NI + i];
  float b = b_in[i];
  float wo = W_out[i];
  P[2 * i] = w0;       P[2 * i + 1] = w0;
  P[128 + 2 * i] = w1; P[128 + 2 * i + 1] = w1;
  P[256 + 2 * i] = b;  P[256 + 2 * i + 1] = b;
  float c0 = wo * w0, c1 = wo * w1;
  P[384 + 2 * i] = c0; P[384 + 2 * i + 1] = c0;
  P[512 + 2 * i] = c1; P[512 + 2 * i + 1] = c1;
  if (i < 2) P[640 + i] = eta[i];
}

__global__ __launch_bounds__(256) void henon8(
    const float4* __restrict__ z, const float* __restrict__ P,
    float4* __restrict__ out, int batch) {
  const v2f* __restrict__ Pw0 = (const v2f*)P;
  const v2f* __restrict__ Pw1 = (const v2f*)(P + 128);
  const v2f* __restrict__ Pb  = (const v2f*)(P + 256);
  const v2f* __restrict__ Pc0 = (const v2f*)(P + 384);
  const v2f* __restrict__ Pc1 = (const v2f*)(P + 512);
  float e0 = P[640], e1 = P[641];

  // Poly constants hoisted into VGPR pairs once (used as "v" asm operands);
  // the multi-constant instruction (x*D5+D4) needs one of the two in VGPR.
  const v2f kD4 = splat(D4);
  const v2f kD5 = splat(D5);
  const v2f kD3 = splat(D3);
  const v2f kD2 = splat(D2);
  const v2f kONE = splat(1.0f);

  int tid = blockIdx.x * blockDim.x + threadIdx.x;
  int nthr = gridDim.x * blockDim.x;
  int ngroups = batch >> 3;

  for (int g = tid; g < ngroups; g += nthr) {
    int r = g << 3;
    float4 v[8];
#pragma unroll
    for (int k = 0; k < 8; ++k) v[k] = z[r + k];

    v2f X0[4], X1[4], Y0[4], Y1[4];
#pragma unroll
    for (int p = 0; p < 4; ++p) {
      X0[p] = (v2f){v[2 * p].x, v[2 * p + 1].x};
      X1[p] = (v2f){v[2 * p].y, v[2 * p + 1].y};
      Y0[p] = (v2f){v[2 * p].z, v[2 * p + 1].z};
      Y1[p] = (v2f){v[2 * p].w, v[2 * p + 1].w};
    }

#pragma unroll 1
    for (int it = 0; it < 4; ++it) {
      v2f g0[4], g1[4];
#pragma unroll
      for (int p = 0; p < 4; ++p) { g0[p] = splat(0.f); g1[p] = splat(0.f); }
#pragma unroll 4
      for (int i = 0; i < NI; ++i) {
        v2f w0 = Pw0[i], w1 = Pw1[i];  // stay in SGPR pairs ("s" operands)
        v2f c0 = Pc0[i], c1 = Pc1[i];  // stay in SGPR pairs ("s" operands)
        v2f bv = Pb[i];                // copied to VGPR pair (c-slot of first fma)
#pragma unroll
        for (int p = 0; p < 4; ++p) {
          v2f t = pk_fma_vsv(Y1[p], w1, bv);
          v2f a = pk_fma_vsv(Y0[p], w0, t);
          v2f x = pk_mul_vv(a, a);
          v2f q = pk_fma_vsv(x, kD5, kD4);  // kD5 via "s"? no: vsv -> b is s
          q = pk_fma_vvs(q, x, kD3);
          q = pk_fma_vvs(q, x, kD2);
          q = pk_fma_vvs(q, x, kONE);
          q = pk_fma_vvs(q, x, kONE);
          v2f s;
          s.x = __builtin_amdgcn_rcpf(q.x);
          s.y = __builtin_amdgcn_rcpf(q.y);
          g0[p] = pk_fma_vsv(s, c0, g0[p]);
          g1[p] = pk_fma_vsv(s, c1, g1[p]);
        }
      }
#pragma unroll
      for (int p = 0; p < 4; ++p) {
        v2f nX0 = Y0[p] + splat(e0);
        v2f nX1 = Y1[p] + splat(e1);
        Y0[p] = g0[p] - X0[p];
        Y1[p] = g1[p] - X1[p];
        X0[p] = nX0;
        X1[p] = nX1;
      }
    }
#pragma unroll
    for (int p = 0; p < 4; ++p) {
      out[r + 2 * p]     = make_float4(X0[p].x, X1[p].x, Y0[p].x, Y1[p].x);
      out[r + 2 * p + 1] = make_float4(X0[p].y, X1[p].y, Y0[p].y, Y1[p].y);
    }
  }

  // Tail rows (batch % 8), scalar path.
  int tail = batch & 7;
  if (tail && tid < tail) {
    int row = (ngroups << 3) + tid;
    float4 v = z[row];
    float X0 = v.x, X1 = v.y, Y0 = v.z, Y1 = v.w;
    for (int it = 0; it < 4; ++it) {
      float g0 = 0.f, g1 = 0.f;
      for (int i = 0; i < NI; ++i) {
        float a = fmaf(Y0, Pw0[i].x, fmaf(Y1, Pw1[i].x, Pb[i].x));
        float x = a * a;
        float q = fmaf(x, D5, D4);
        q = fmaf(q, x, D3);
        q = fmaf(q, x, D2);
        q = fmaf(q, x, 1.0f);
        q = fmaf(q, x, 1.0f);
        float s = __builtin_amdgcn_rcpf(q);
        g0 = fmaf(s, Pc0[i].x, g0);
        g1 = fmaf(s, Pc1[i].x, g1);
      }
      float nX0 = Y0 + e0, nX1 = Y1 + e1;
      Y0 = g0 - X0;
      Y1 = g1 - X1;
      X0 = nX0;
      X1 = nX1;
    }
    out[row] = make_float4(X0, X1, Y0, Y1);
  }
}

// Fallback if ws too small for the table: raw weights, 1 row/thread.
__global__ __launch_bounds__(256) void henon_raw(
    const float4* __restrict__ z, const float* __restrict__ W_in,
    const float* __restrict__ W_out, const float* __restrict__ b_in,
    const float* __restrict__ eta, float4* __restrict__ out, int batch) {
  int idx = blockIdx.x * blockDim.x + threadIdx.x;
  int stride = gridDim.x * blockDim.x;
  float e0 = eta[0], e1 = eta[1];
  for (int row = idx; row < batch; row += stride) {
    float4 v = z[row];
    float X0 = v.x, X1 = v.y, Y0 = v.z, Y1 = v.w;
    for (int it = 0; it < 4; ++it) {
      float g0 = 0.f, g1 = 0.f;
#pragma unroll
      for (int i = 0; i < NI; ++i) {
        float w0 = W_in[i], w1 = W_in[NI + i];
        float a = fmaf(Y0, w0, fmaf(Y1, w1, b_in[i]));
        float x = a * a;
        float q = fmaf(x, D5, D4);
        q = fmaf(q, x, D3);
        q = fmaf(q, x, D2);
        q = fmaf(q, x, 1.0f);
        q = fmaf(q, x, 1.0f);
        float s = __builtin_amdgcn_rcpf(q) * W_out[i];
        g0 = fmaf(s, w0, g0);
        g1 = fmaf(s, w1, g1);
      }
      float nX0 = Y0 + e0, nX1 = Y1 + e1;
      Y0 = g0 - X0;
      Y1 = g1 - X1;
      X0 = nX0;
      X1 = nX1;
    }
    out[row] = make_float4(X0, X1, Y0, Y1);
  }
}

extern "C" void kernel_launch(void* const* d_in, const int* in_sizes, int n_in,
                              void* d_out, int out_size, void* d_ws, size_t ws_size,
                              hipStream_t stream) {
  const float4* z = (const float4*)d_in[0];
  const float* W_in = (const float*)d_in[1];
  const float* W_out = (const float*)d_in[2];
  const float* b_in = (const float*)d_in[3];
  const float* eta = (const float*)d_in[4];
  float4* out = (float4*)d_out;

  int batch = in_sizes[0] / 4;  // 2,000,000 rows

  if (ws_size >= 642 * sizeof(float)) {
    float* P = (float*)d_ws;
    henon_prep<<<1, 64, 0, stream>>>(W_in, W_out, b_in, eta, P);
    int ngroups = (batch + 7) >> 3;
    int blocks = (ngroups + 255) / 256;
    henon8<<<blocks, 256, 0, stream>>>(z, P, out, batch);
  } else {
    int blocks = (batch + 255) / 256;
    henon_raw<<<blocks, 256, 0, stream>>>(z, W_in, W_out, b_in, eta, out, batch);
  }
}